// Round 6
// baseline (234.679 us; speedup 1.0000x reference)
//
#include <hip/hip_runtime.h>
#include <hip/hip_cooperative_groups.h>

namespace cg = cooperative_groups;

typedef float v2f __attribute__((ext_vector_type(2)));
#define FMA2(a,b,c) __builtin_elementwise_fma((a),(b),(c))
#define MAX2(a,b)   __builtin_elementwise_max((a),(b))

#define SPOS 2500
#define SSTRIDE 2560                 // padded column count for LC rows
#define NSLICE 4
// ws layout (floats): LC float4[32][SSTRIDE] | A[64] | WoT[4096] | part[256*8*4*16]
#define WS_A_OFF    (32 * SSTRIDE * 4)
#define WS_WOT_OFF  (WS_A_OFF + 64)
#define WS_PART_OFF (WS_WOT_OFF + 4096)
#define SCL (0.35355339059327373f * 1.4426950408889634f)   // 1/sqrt(8) * log2(e)

// Fused cooperative kernel, 512 blocks x 256 threads (<=2 blocks/CU needed).
// Phase 0: scores are quadratic in x (exp2 domain): sc = A*x^2 + L*x + C.
//          L,C depend only on pe -> shared by all 256 batches. Also A, WoT.
// Phase 1: wave = (head, 4-batch group); lane = position. Accumulates only
//          P0[nb][t] = sum_s p and P1[nb][t] = sum_s x*p (PV contraction is
//          deferred: pooled = (P1@wv + P0@bv)/S).
// Phase 2: per batch: sum slice partials -> wv/bv contraction -> mean ->
//          @Wo^T (coalesced WoT) + bo -> LayerNorm.
__global__ __launch_bounds__(256) void attn_pool_fused(
    const float* __restrict__ sim,
    const float* __restrict__ wq, const float* __restrict__ bq,
    const float* __restrict__ wk, const float* __restrict__ bk,
    const float* __restrict__ wv, const float* __restrict__ bv,
    const float* __restrict__ pe, const float* __restrict__ Wo,
    const float* __restrict__ bo,
    const float* __restrict__ gamma, const float* __restrict__ beta,
    float* __restrict__ ws, float* __restrict__ out)
{
    cg::grid_group grid = cg::this_grid();
    const int tid  = threadIdx.x;
    const int gidx = blockIdx.x * 256 + tid;   // 0..131071

    // ---------------- Phase 0: LC / A / WoT precompute ----------------
    if (gidx < SPOS * 8) {
        const int s = gidx >> 3, h = gidx & 7;

        float per[64];
        const float4* p4 = (const float4*)(pe + (size_t)s * 64);
        #pragma unroll
        for (int j = 0; j < 16; ++j) {
            const float4 t = p4[j];
            per[4*j] = t.x; per[4*j+1] = t.y; per[4*j+2] = t.z; per[4*j+3] = t.w;
        }

        float eq[8];
        #pragma unroll
        for (int d = 0; d < 8; ++d) eq[d] = bq[h*8+d] + per[h*8+d];

        float Lr[8], Cr[8];
        #pragma unroll
        for (int t = 0; t < 8; ++t) {
            float l = 0.f, cc = 0.f;
            #pragma unroll
            for (int d = 0; d < 8; ++d) {
                const float ek = bk[t*8+d] + per[t*8+d];
                l  = fmaf(wq[h*8+d], ek,    l);
                l  = fmaf(wk[t*8+d], eq[d], l);
                cc = fmaf(eq[d], ek, cc);
            }
            Lr[t] = l * SCL; Cr[t] = cc * SCL;
        }

        float4* lc4 = (float4*)ws;
        #pragma unroll
        for (int t2 = 0; t2 < 4; ++t2)
            lc4[(size_t)(h*4+t2) * SSTRIDE + s] =
                make_float4(Lr[2*t2], Lr[2*t2+1], Cr[2*t2], Cr[2*t2+1]);

        if (gidx < 64) {
            const int hh = gidx >> 3, tt = gidx & 7;
            float a = 0.f;
            #pragma unroll
            for (int d = 0; d < 8; ++d) a = fmaf(wq[hh*8+d], wk[tt*8+d], a);
            ws[WS_A_OFF + gidx] = a * SCL;
        }
    } else if (gidx >= 20480 && gidx < 20480 + 4096) {
        const int i = gidx - 20480;          // i = j*64 + f
        const int j = i >> 6, f = i & 63;
        ws[WS_WOT_OFF + i] = Wo[(size_t)f * 64 + j];   // WoT[j][f]
    }

    __threadfence();
    grid.sync();

    // ---------------- Phase 1: P0/P1 accumulation ----------------
    {
        const int bg   = blockIdx.x >> 3;          // 0..63: batches bg*4..bg*4+3
        const int sl   = (blockIdx.x >> 1) & 3;    // slice 0..3 (625 positions)
        const int hq   = blockIdx.x & 1;
        const int wave = tid >> 6;
        const int lane = tid & 63;
        const int h    = hq * 4 + wave;            // head 0..7

        const int s_begin = sl * 625;
        const int s_end   = s_begin + 625;

        const float4* lch = (const float4*)ws + (size_t)(h * 4) * SSTRIDE;

        // A row for this head -> 8 SGPRs (readfirstlane)
        float aA[8];
        #pragma unroll
        for (int i = 0; i < 8; ++i)
            aA[i] = __int_as_float(__builtin_amdgcn_readfirstlane(
                        __float_as_int(ws[WS_A_OFF + h * 8 + i])));

        v2f P0[16], P1[16];   // [nb][t2]
        #pragma unroll
        for (int i = 0; i < 16; ++i) { P0[i] = (v2f)(0.f); P1[i] = (v2f)(0.f); }

        const float* simb = sim + (size_t)(bg * 4) * SPOS;

        #pragma unroll 1
        for (int it = 0; it < 10; ++it) {
            const int s = s_begin + it * 64 + lane;
            if (s < s_end) {
                float4 q[4];
                #pragma unroll
                for (int t2 = 0; t2 < 4; ++t2) q[t2] = lch[t2 * SSTRIDE + s];
                float xb[4];
                #pragma unroll
                for (int nb = 0; nb < 4; ++nb) xb[nb] = simb[nb * SPOS + s];

                #pragma unroll
                for (int nb = 0; nb < 4; ++nb) {
                    const float x = xb[nb];
                    const v2f xx = {x, x};
                    v2f e[4];
                    #pragma unroll
                    for (int t2 = 0; t2 < 4; ++t2) {
                        // Horner ((A*x + L)*x + C); first step scalar: A in SGPR
                        const float u0 = fmaf(x, aA[2*t2],   q[t2].x);
                        const float u1 = fmaf(x, aA[2*t2+1], q[t2].y);
                        const v2f uu = {u0, u1};
                        const v2f cv = {q[t2].z, q[t2].w};
                        e[t2] = FMA2(uu, xx, cv);
                    }
                    const v2f m2 = MAX2(MAX2(e[0], e[1]), MAX2(e[2], e[3]));
                    const float m = fmaxf(m2.x, m2.y);
                    const v2f ms = {m, m};
                    v2f den2 = (v2f)(0.f);
                    #pragma unroll
                    for (int t2 = 0; t2 < 4; ++t2) {
                        v2f ee = e[t2] - ms;
                        ee.x = exp2f(ee.x); ee.y = exp2f(ee.y);
                        e[t2] = ee; den2 += ee;
                    }
                    const float inv  = __builtin_amdgcn_rcpf(den2.x + den2.y);
                    const float xinv = x * inv;
                    const v2f vi = {inv, inv}, vx = {xinv, xinv};
                    #pragma unroll
                    for (int t2 = 0; t2 < 4; ++t2) {
                        P0[nb*4+t2] = FMA2(vi, e[t2], P0[nb*4+t2]);
                        P1[nb*4+t2] = FMA2(vx, e[t2], P1[nb*4+t2]);
                    }
                }
            }
        }

        // Flatten: av[nb*16 + t] = P0[nb][t], av[nb*16 + 8 + t] = P1[nb][t]
        float av[64];
        #pragma unroll
        for (int nb = 0; nb < 4; ++nb)
            #pragma unroll
            for (int t = 0; t < 8; ++t) {
                av[nb*16 + t]     = (t & 1) ? P0[nb*4 + (t>>1)].y : P0[nb*4 + (t>>1)].x;
                av[nb*16 + 8 + t] = (t & 1) ? P1[nb*4 + (t>>1)].y : P1[nb*4 + (t>>1)].x;
            }

        // Halving-butterfly across 64 lanes; lane ends with index bitrev6(lane).
        float r32[32];
        #pragma unroll
        for (int i = 0; i < 32; ++i) {
            const bool up = (lane & 1) != 0;
            const float keep = up ? av[i+32] : av[i];
            const float send = up ? av[i]    : av[i+32];
            r32[i] = keep + __shfl_xor(send, 1, 64);
        }
        float r16[16];
        #pragma unroll
        for (int i = 0; i < 16; ++i) {
            const bool up = (lane & 2) != 0;
            const float keep = up ? r32[i+16] : r32[i];
            const float send = up ? r32[i]    : r32[i+16];
            r16[i] = keep + __shfl_xor(send, 2, 64);
        }
        float r8[8];
        #pragma unroll
        for (int i = 0; i < 8; ++i) {
            const bool up = (lane & 4) != 0;
            const float keep = up ? r16[i+8] : r16[i];
            const float send = up ? r16[i]   : r16[i+8];
            r8[i] = keep + __shfl_xor(send, 4, 64);
        }
        float r4[4];
        #pragma unroll
        for (int i = 0; i < 4; ++i) {
            const bool up = (lane & 8) != 0;
            const float keep = up ? r8[i+4] : r8[i];
            const float send = up ? r8[i]   : r8[i+4];
            r4[i] = keep + __shfl_xor(send, 8, 64);
        }
        float r2[2];
        #pragma unroll
        for (int i = 0; i < 2; ++i) {
            const bool up = (lane & 16) != 0;
            const float keep = up ? r4[i+2] : r4[i];
            const float send = up ? r4[i]   : r4[i+2];
            r2[i] = keep + __shfl_xor(send, 16, 64);
        }
        float r1;
        {
            const bool up = (lane & 32) != 0;
            const float keep = up ? r2[1] : r2[0];
            const float send = up ? r2[0] : r2[1];
            r1 = keep + __shfl_xor(send, 32, 64);
        }

        const int f = ((lane & 1) << 5) | ((lane & 2) << 3) | ((lane & 4) << 1)
                    | ((lane & 8) >> 1) | ((lane & 16) >> 3) | ((lane & 32) >> 5);
        const int nb = f >> 4, rem = f & 15;
        ws[WS_PART_OFF +
           ((((size_t)(bg*4 + nb) * 8 + h) * NSLICE + sl) * 16 + rem)] = r1;
    }

    __threadfence();
    grid.sync();

    // ---------------- Phase 2: contraction + matvec + LayerNorm ----------------
    if (blockIdx.x < 256 && tid < 64) {
        const float* part = ws + WS_PART_OFF;
        const float* WoT  = ws + WS_WOT_OFF;
        const int b = blockIdx.x;
        const int l = tid;                   // as (h,t) for partials, (h,d) for pooled
        const int h = l >> 3, t = l & 7, d = t;

        float p0 = 0.f, p1 = 0.f;            // P0[h][t], P1[h][t]
        #pragma unroll
        for (int sl = 0; sl < NSLICE; ++sl) {
            const size_t base = (((size_t)b * 8 + h) * NSLICE + sl) * 16;
            p0 += part[base + t];
            p1 += part[base + 8 + t];
        }

        // pooled[h,d] = (sum_t P1[h][t]*wv[t,d] + P0[h][t]*bv[t,d]) / S
        float pool = 0.f;
        #pragma unroll
        for (int tt = 0; tt < 8; ++tt) {
            const float P1v = __shfl(p1, h*8 + tt, 64);
            const float P0v = __shfl(p0, h*8 + tt, 64);
            pool = fmaf(P1v, wv[tt*8 + d], pool);
            pool = fmaf(P0v, bv[tt*8 + d], pool);
        }
        pool *= (1.0f / 2500.0f);

        float y = bo[l];
        #pragma unroll
        for (int j = 0; j < 64; ++j) {
            const float pj = __shfl(pool, j, 64);
            y = fmaf(pj, WoT[j * 64 + l], y);     // coalesced across lanes
        }

        float s1 = y;
        #pragma unroll
        for (int off = 32; off > 0; off >>= 1) s1 += __shfl_xor(s1, off, 64);
        const float mu = s1 * (1.0f / 64.0f);
        const float dlt = y - mu;
        float s2 = dlt * dlt;
        #pragma unroll
        for (int off = 32; off > 0; off >>= 1) s2 += __shfl_xor(s2, off, 64);
        const float var = s2 * (1.0f / 64.0f);

        out[(size_t)b * 64 + l] = dlt * rsqrtf(var + 1e-5f) * gamma[l] + beta[l];
    }
}

extern "C" void kernel_launch(void* const* d_in, const int* in_sizes, int n_in,
                              void* d_out, int out_size, void* d_ws, size_t ws_size,
                              hipStream_t stream) {
    const float* sim   = (const float*)d_in[0];
    const float* wq    = (const float*)d_in[1];
    const float* bq    = (const float*)d_in[2];
    const float* wk    = (const float*)d_in[3];
    const float* bk    = (const float*)d_in[4];
    const float* wv    = (const float*)d_in[5];
    const float* bv    = (const float*)d_in[6];
    const float* pe    = (const float*)d_in[7];
    const float* Wo    = (const float*)d_in[8];
    const float* bo    = (const float*)d_in[9];
    const float* gamma = (const float*)d_in[10];
    const float* beta  = (const float*)d_in[11];
    float* ws  = (float*)d_ws;                 // ~1.9 MB used
    float* out = (float*)d_out;

    void* args[] = {
        (void*)&sim, (void*)&wq, (void*)&bq, (void*)&wk, (void*)&bk,
        (void*)&wv, (void*)&bv, (void*)&pe, (void*)&Wo, (void*)&bo,
        (void*)&gamma, (void*)&beta, (void*)&ws, (void*)&out
    };
    hipLaunchCooperativeKernel((const void*)attn_pool_fused,
                               dim3(512), dim3(256), args, 0, stream);
}

// Round 7
// 207.693 us; speedup vs baseline: 1.1299x; 1.1299x over previous
//
#include <hip/hip_runtime.h>

typedef float v2f __attribute__((ext_vector_type(2)));
#define FMA2(a,b,c) __builtin_elementwise_fma((a),(b),(c))
#define MAX2(a,b)   __builtin_elementwise_max((a),(b))

#define SPOS 2500
#define SSTRIDE 2560                 // padded column count for LC rows
#define NSLICE 6
#define SLICE_LEN 417                // ceil(2500/6)
#define NBLOCKS 768                  // 64 bg x 6 sl x 2 hq; <=3 blocks/CU co-resident
// ws layout (floats): LC float4[32][SSTRIDE] | A[64] | WoT[4096] | part[256*8*6*16]
#define WS_A_OFF    (32 * SSTRIDE * 4)
#define WS_WOT_OFF  (WS_A_OFF + 64)
#define WS_PART_OFF (WS_WOT_OFF + 4096)
#define SCL (0.35355339059327373f * 1.4426950408889634f)   // 1/sqrt(8) * log2(e)

// Grid-barrier state. Zero-initialized at module load; block 0 resets to 0 at
// the end of every launch (guarded by the exit counter), so each graph replay
// starts clean without a memset node.
__device__ int g_bar[4];

static __device__ __forceinline__ void grid_barrier(int idx, int tid) {
    __syncthreads();
    if (tid == 0) {
        __threadfence();   // release: publish this block's writes (L2 writeback)
        __hip_atomic_fetch_add(&g_bar[idx], 1, __ATOMIC_ACQ_REL,
                               __HIP_MEMORY_SCOPE_AGENT);
        while (__hip_atomic_fetch_add(&g_bar[idx], 0, __ATOMIC_RELAXED,
                                      __HIP_MEMORY_SCOPE_AGENT) < NBLOCKS)
            __builtin_amdgcn_s_sleep(4);
        __threadfence();   // acquire: invalidate so we see remote writes
    }
    __syncthreads();
}

// Fused kernel (regular launch, no cooperative groups).
// Phase 0: scores quadratic in x (exp2 domain): sc = A*x^2 + L*x + C;
//          L,C depend only on pe (shared by all 256 batches). Also A, WoT.
// Phase 1: wave = (head, 4-batch group); lane = position. Accumulates only
//          P0[nb][t] = sum_s p and P1[nb][t] = sum_s x*p.
// Phase 2: per batch: slice-sum -> wv/bv contraction -> mean -> @WoT + bo -> LN.
__global__ __launch_bounds__(256, 3) void attn_pool_fused(
    const float* __restrict__ sim,
    const float* __restrict__ wq, const float* __restrict__ bq,
    const float* __restrict__ wk, const float* __restrict__ bk,
    const float* __restrict__ wv, const float* __restrict__ bv,
    const float* __restrict__ pe, const float* __restrict__ Wo,
    const float* __restrict__ bo,
    const float* __restrict__ gamma, const float* __restrict__ beta,
    float* __restrict__ ws, float* __restrict__ out)
{
    const int tid  = threadIdx.x;
    const int gidx = blockIdx.x * 256 + tid;   // 0..196607

    // ---------------- Phase 0: LC / A / WoT precompute ----------------
    if (gidx < SPOS * 8) {
        const int s = gidx >> 3, h = gidx & 7;

        float per[64];
        const float4* p4 = (const float4*)(pe + (size_t)s * 64);
        #pragma unroll
        for (int j = 0; j < 16; ++j) {
            const float4 t = p4[j];
            per[4*j] = t.x; per[4*j+1] = t.y; per[4*j+2] = t.z; per[4*j+3] = t.w;
        }

        float eq[8];
        #pragma unroll
        for (int d = 0; d < 8; ++d) eq[d] = bq[h*8+d] + per[h*8+d];

        float Lr[8], Cr[8];
        #pragma unroll
        for (int t = 0; t < 8; ++t) {
            float l = 0.f, cc = 0.f;
            #pragma unroll
            for (int d = 0; d < 8; ++d) {
                const float ek = bk[t*8+d] + per[t*8+d];
                l  = fmaf(wq[h*8+d], ek,    l);
                l  = fmaf(wk[t*8+d], eq[d], l);
                cc = fmaf(eq[d], ek, cc);
            }
            Lr[t] = l * SCL; Cr[t] = cc * SCL;
        }

        float4* lc4 = (float4*)ws;
        #pragma unroll
        for (int t2 = 0; t2 < 4; ++t2)
            lc4[(size_t)(h*4+t2) * SSTRIDE + s] =
                make_float4(Lr[2*t2], Lr[2*t2+1], Cr[2*t2], Cr[2*t2+1]);

        if (gidx < 64) {
            const int hh = gidx >> 3, tt = gidx & 7;
            float a = 0.f;
            #pragma unroll
            for (int d = 0; d < 8; ++d) a = fmaf(wq[hh*8+d], wk[tt*8+d], a);
            ws[WS_A_OFF + gidx] = a * SCL;
        }
    } else if (gidx >= 20480 && gidx < 20480 + 4096) {
        const int i = gidx - 20480;          // i = j*64 + f
        const int j = i >> 6, f = i & 63;
        ws[WS_WOT_OFF + i] = Wo[(size_t)f * 64 + j];   // WoT[j][f]
    }

    grid_barrier(0, tid);

    // ---------------- Phase 1: P0/P1 accumulation ----------------
    {
        const int bg   = blockIdx.x / 12;          // 0..63: batches bg*4..bg*4+3
        const int r    = blockIdx.x - bg * 12;
        const int sl   = r >> 1;                   // slice 0..5
        const int hq   = r & 1;
        const int wave = tid >> 6;
        const int lane = tid & 63;
        const int h    = hq * 4 + wave;            // head 0..7

        const int s_begin = sl * SLICE_LEN;
        const int s_end   = min(s_begin + SLICE_LEN, SPOS);

        const float4* lch = (const float4*)ws + (size_t)(h * 4) * SSTRIDE;

        // A row for this head -> 8 SGPRs (readfirstlane)
        float aA[8];
        #pragma unroll
        for (int i = 0; i < 8; ++i)
            aA[i] = __int_as_float(__builtin_amdgcn_readfirstlane(
                        __float_as_int(ws[WS_A_OFF + h * 8 + i])));

        v2f P0[16], P1[16];   // [nb][t2]
        #pragma unroll
        for (int i = 0; i < 16; ++i) { P0[i] = (v2f)(0.f); P1[i] = (v2f)(0.f); }

        const float* simb = sim + (size_t)(bg * 4) * SPOS;

        #pragma unroll 1
        for (int it = 0; it < 7; ++it) {
            const int s = s_begin + it * 64 + lane;
            if (s < s_end) {
                float4 q[4];
                #pragma unroll
                for (int t2 = 0; t2 < 4; ++t2) q[t2] = lch[t2 * SSTRIDE + s];
                float xb[4];
                #pragma unroll
                for (int nb = 0; nb < 4; ++nb) xb[nb] = simb[nb * SPOS + s];

                #pragma unroll
                for (int nb = 0; nb < 4; ++nb) {
                    const float x = xb[nb];
                    const v2f xx = {x, x};
                    v2f e[4];
                    #pragma unroll
                    for (int t2 = 0; t2 < 4; ++t2) {
                        // Horner ((A*x + L)*x + C); first step scalar: A in SGPR
                        const float u0 = fmaf(x, aA[2*t2],   q[t2].x);
                        const float u1 = fmaf(x, aA[2*t2+1], q[t2].y);
                        const v2f uu = {u0, u1};
                        const v2f cv = {q[t2].z, q[t2].w};
                        e[t2] = FMA2(uu, xx, cv);
                    }
                    const v2f m2 = MAX2(MAX2(e[0], e[1]), MAX2(e[2], e[3]));
                    const float m = fmaxf(m2.x, m2.y);
                    const v2f ms = {m, m};
                    v2f den2 = (v2f)(0.f);
                    #pragma unroll
                    for (int t2 = 0; t2 < 4; ++t2) {
                        v2f ee = e[t2] - ms;
                        ee.x = exp2f(ee.x); ee.y = exp2f(ee.y);
                        e[t2] = ee; den2 += ee;
                    }
                    const float inv  = __builtin_amdgcn_rcpf(den2.x + den2.y);
                    const float xinv = x * inv;
                    const v2f vi = {inv, inv}, vx = {xinv, xinv};
                    #pragma unroll
                    for (int t2 = 0; t2 < 4; ++t2) {
                        P0[nb*4+t2] = FMA2(vi, e[t2], P0[nb*4+t2]);
                        P1[nb*4+t2] = FMA2(vx, e[t2], P1[nb*4+t2]);
                    }
                }
            }
        }

        // Flatten: av[nb*16 + t] = P0[nb][t], av[nb*16 + 8 + t] = P1[nb][t]
        float av[64];
        #pragma unroll
        for (int nb = 0; nb < 4; ++nb)
            #pragma unroll
            for (int t = 0; t < 8; ++t) {
                av[nb*16 + t]     = (t & 1) ? P0[nb*4 + (t>>1)].y : P0[nb*4 + (t>>1)].x;
                av[nb*16 + 8 + t] = (t & 1) ? P1[nb*4 + (t>>1)].y : P1[nb*4 + (t>>1)].x;
            }

        // Halving-butterfly across 64 lanes; lane ends with index bitrev6(lane).
        float r32[32];
        #pragma unroll
        for (int i = 0; i < 32; ++i) {
            const bool up = (lane & 1) != 0;
            const float keep = up ? av[i+32] : av[i];
            const float send = up ? av[i]    : av[i+32];
            r32[i] = keep + __shfl_xor(send, 1, 64);
        }
        float r16[16];
        #pragma unroll
        for (int i = 0; i < 16; ++i) {
            const bool up = (lane & 2) != 0;
            const float keep = up ? r32[i+16] : r32[i];
            const float send = up ? r32[i]    : r32[i+16];
            r16[i] = keep + __shfl_xor(send, 2, 64);
        }
        float r8[8];
        #pragma unroll
        for (int i = 0; i < 8; ++i) {
            const bool up = (lane & 4) != 0;
            const float keep = up ? r16[i+8] : r16[i];
            const float send = up ? r16[i]   : r16[i+8];
            r8[i] = keep + __shfl_xor(send, 4, 64);
        }
        float r4[4];
        #pragma unroll
        for (int i = 0; i < 4; ++i) {
            const bool up = (lane & 8) != 0;
            const float keep = up ? r8[i+4] : r8[i];
            const float send = up ? r8[i]   : r8[i+4];
            r4[i] = keep + __shfl_xor(send, 8, 64);
        }
        float r2[2];
        #pragma unroll
        for (int i = 0; i < 2; ++i) {
            const bool up = (lane & 16) != 0;
            const float keep = up ? r4[i+2] : r4[i];
            const float send = up ? r4[i]   : r4[i+2];
            r2[i] = keep + __shfl_xor(send, 16, 64);
        }
        float r1;
        {
            const bool up = (lane & 32) != 0;
            const float keep = up ? r2[1] : r2[0];
            const float send = up ? r2[0] : r2[1];
            r1 = keep + __shfl_xor(send, 32, 64);
        }

        const int f = ((lane & 1) << 5) | ((lane & 2) << 3) | ((lane & 4) << 1)
                    | ((lane & 8) >> 1) | ((lane & 16) >> 3) | ((lane & 32) >> 5);
        const int nb = f >> 4, rem = f & 15;
        ws[WS_PART_OFF +
           ((((size_t)(bg*4 + nb) * 8 + h) * NSLICE + sl) * 16 + rem)] = r1;
    }

    grid_barrier(1, tid);

    // ---------------- Phase 2: contraction + matvec + LayerNorm ----------------
    if (blockIdx.x < 256 && tid < 64) {
        const float* part = ws + WS_PART_OFF;
        const float* WoT  = ws + WS_WOT_OFF;
        const int b = blockIdx.x;
        const int l = tid;                   // (h,t) for partials, (h,d) for pooled
        const int h = l >> 3, t = l & 7, d = t;

        float p0 = 0.f, p1 = 0.f;            // P0[h][t], P1[h][t]
        #pragma unroll
        for (int sl = 0; sl < NSLICE; ++sl) {
            const size_t base = (((size_t)b * 8 + h) * NSLICE + sl) * 16;
            p0 += part[base + t];
            p1 += part[base + 8 + t];
        }

        // pooled[h,d] = (sum_t P1[h][t]*wv[t,d] + P0[h][t]*bv[t,d]) / S
        float pool = 0.f;
        #pragma unroll
        for (int tt = 0; tt < 8; ++tt) {
            const float P1v = __shfl(p1, h*8 + tt, 64);
            const float P0v = __shfl(p0, h*8 + tt, 64);
            pool = fmaf(P1v, wv[tt*8 + d], pool);
            pool = fmaf(P0v, bv[tt*8 + d], pool);
        }
        pool *= (1.0f / 2500.0f);

        float y = bo[l];
        #pragma unroll
        for (int j = 0; j < 64; ++j) {
            const float pj = __shfl(pool, j, 64);
            y = fmaf(pj, WoT[j * 64 + l], y);     // coalesced across lanes
        }

        float s1 = y;
        #pragma unroll
        for (int off = 32; off > 0; off >>= 1) s1 += __shfl_xor(s1, off, 64);
        const float mu = s1 * (1.0f / 64.0f);
        const float dlt = y - mu;
        float s2 = dlt * dlt;
        #pragma unroll
        for (int off = 32; off > 0; off >>= 1) s2 += __shfl_xor(s2, off, 64);
        const float var = s2 * (1.0f / 64.0f);

        out[(size_t)b * 64 + l] = dlt * rsqrtf(var + 1e-5f) * gamma[l] + beta[l];
    }

    // ---------------- Exit: self-reset barrier counters ----------------
    __syncthreads();
    if (tid == 0) {
        __threadfence();
        __hip_atomic_fetch_add(&g_bar[2], 1, __ATOMIC_ACQ_REL,
                               __HIP_MEMORY_SCOPE_AGENT);
        if (blockIdx.x == 0) {
            while (__hip_atomic_fetch_add(&g_bar[2], 0, __ATOMIC_RELAXED,
                                          __HIP_MEMORY_SCOPE_AGENT) < NBLOCKS)
                __builtin_amdgcn_s_sleep(4);
            __hip_atomic_store(&g_bar[0], 0, __ATOMIC_RELAXED, __HIP_MEMORY_SCOPE_AGENT);
            __hip_atomic_store(&g_bar[1], 0, __ATOMIC_RELAXED, __HIP_MEMORY_SCOPE_AGENT);
            __hip_atomic_store(&g_bar[2], 0, __ATOMIC_RELAXED, __HIP_MEMORY_SCOPE_AGENT);
        }
    }
}

extern "C" void kernel_launch(void* const* d_in, const int* in_sizes, int n_in,
                              void* d_out, int out_size, void* d_ws, size_t ws_size,
                              hipStream_t stream) {
    const float* sim   = (const float*)d_in[0];
    const float* wq    = (const float*)d_in[1];
    const float* bq    = (const float*)d_in[2];
    const float* wk    = (const float*)d_in[3];
    const float* bk    = (const float*)d_in[4];
    const float* wv    = (const float*)d_in[5];
    const float* bv    = (const float*)d_in[6];
    const float* pe    = (const float*)d_in[7];
    const float* Wo    = (const float*)d_in[8];
    const float* bo    = (const float*)d_in[9];
    const float* gamma = (const float*)d_in[10];
    const float* beta  = (const float*)d_in[11];
    float* ws  = (float*)d_ws;                 // ~2 MB used
    float* out = (float*)d_out;

    attn_pool_fused<<<dim3(NBLOCKS), dim3(256), 0, stream>>>(
        sim, wq, bq, wk, bk, wv, bv, pe, Wo, bo, gamma, beta, ws, out);
}

// Round 8
// 152.887 us; speedup vs baseline: 1.5350x; 1.3585x over previous
//
#include <hip/hip_runtime.h>

typedef float v2f __attribute__((ext_vector_type(2)));
#define FMA2(a,b,c) __builtin_elementwise_fma((a),(b),(c))
#define MAX2(a,b)   __builtin_elementwise_max((a),(b))

#define SPOS 2500
#define SSTRIDE 2560                 // padded column count for LC rows
#define NSLICE 6
#define SLICE_LEN 417                // ceil(2500/6)
#define NBLOCKS 768                  // 64 bg x 6 sl x 2 hq; exactly 3 blocks/CU
// ws layout (floats): LC float4[32][SSTRIDE] | A[64] | WoT[4096] | part[256*8*6*16]
#define WS_A_OFF    (32 * SSTRIDE * 4)
#define WS_WOT_OFF  (WS_A_OFF + 64)
#define WS_PART_OFF (WS_WOT_OFF + 4096)
#define SCL (0.35355339059327373f * 1.4426950408889634f)   // 1/sqrt(8) * log2(e)

// Monotonic synchronization state (never reset; zero-initialized at module
// load). Kernel launches serialize on the stream, so each launch's arrivals
// occupy a clean contiguous ticket range -> generation = ticket/N + 1.
__device__ int g_bar0;      // grid barrier after phase 0 (768 arrivals/launch)
__device__ int g_cnt[64];   // per-bg completion counters (12 arrivals/launch)

// Fused kernel. amdgpu_waves_per_eu(3,3) pins the allocator to a 3-waves/EU
// budget (<=170 VGPR): phase 1 needs ~120 live regs; R6/R7 showed that
// without the max, the allocator squeezes to 64 and spills the accumulators.
__global__ __attribute__((amdgpu_flat_work_group_size(256, 256),
                          amdgpu_waves_per_eu(3, 3)))
void attn_pool_fused(
    const float* __restrict__ sim,
    const float* __restrict__ wq, const float* __restrict__ bq,
    const float* __restrict__ wk, const float* __restrict__ bk,
    const float* __restrict__ wv, const float* __restrict__ bv,
    const float* __restrict__ pe, const float* __restrict__ Wo,
    const float* __restrict__ bo,
    const float* __restrict__ gamma, const float* __restrict__ beta,
    float* __restrict__ ws, float* __restrict__ out)
{
    const int tid = threadIdx.x;

    // ---- Phase 0: LC / A / WoT precompute, spread evenly over all blocks ----
    // item = blockIdx.x*32 + t for t<32: 768*32 = 24576 items total.
    if (tid < 32) {
        const int item = blockIdx.x * 32 + tid;
        if (item < SPOS * 8) {
            const int s = item >> 3, h = item & 7;

            float per[64];
            const float4* p4 = (const float4*)(pe + (size_t)s * 64);
            #pragma unroll
            for (int j = 0; j < 16; ++j) {
                const float4 t4 = p4[j];
                per[4*j] = t4.x; per[4*j+1] = t4.y; per[4*j+2] = t4.z; per[4*j+3] = t4.w;
            }

            float eq[8];
            #pragma unroll
            for (int d = 0; d < 8; ++d) eq[d] = bq[h*8+d] + per[h*8+d];

            float Lr[8], Cr[8];
            #pragma unroll
            for (int t = 0; t < 8; ++t) {
                float l = 0.f, cc = 0.f;
                #pragma unroll
                for (int d = 0; d < 8; ++d) {
                    const float ek = bk[t*8+d] + per[t*8+d];
                    l  = fmaf(wq[h*8+d], ek,    l);
                    l  = fmaf(wk[t*8+d], eq[d], l);
                    cc = fmaf(eq[d], ek, cc);
                }
                Lr[t] = l * SCL; Cr[t] = cc * SCL;
            }

            float4* lc4 = (float4*)ws;
            #pragma unroll
            for (int t2 = 0; t2 < 4; ++t2)
                lc4[(size_t)(h*4+t2) * SSTRIDE + s] =
                    make_float4(Lr[2*t2], Lr[2*t2+1], Cr[2*t2], Cr[2*t2+1]);
        } else if (item < SPOS * 8 + 4096) {
            const int i = item - SPOS * 8;       // i = j*64 + f
            const int j = i >> 6, f = i & 63;
            ws[WS_WOT_OFF + i] = Wo[(size_t)f * 64 + j];   // WoT[j][f]
        } else if (item < SPOS * 8 + 4096 + 64) {
            const int i = item - (SPOS * 8 + 4096);
            const int hh = i >> 3, tt = i & 7;
            float a = 0.f;
            #pragma unroll
            for (int d = 0; d < 8; ++d) a = fmaf(wq[hh*8+d], wk[tt*8+d], a);
            ws[WS_A_OFF + i] = a * SCL;
        }
    }

    // ---- Grid barrier (monotonic tickets, load-polling) ----
    __syncthreads();
    if (tid == 0) {
        __threadfence();
        const int t = __hip_atomic_fetch_add(&g_bar0, 1, __ATOMIC_ACQ_REL,
                                             __HIP_MEMORY_SCOPE_AGENT);
        const int target = (t / NBLOCKS + 1) * NBLOCKS;
        while (__hip_atomic_load(&g_bar0, __ATOMIC_ACQUIRE,
                                 __HIP_MEMORY_SCOPE_AGENT) < target)
            __builtin_amdgcn_s_sleep(2);
        __threadfence();
    }
    __syncthreads();

    // ---- Phase 1: P0/P1 accumulation ----
    const int bg   = blockIdx.x / 12;          // 0..63: batches bg*4..bg*4+3
    {
        const int r    = blockIdx.x - bg * 12;
        const int sl   = r >> 1;                   // slice 0..5
        const int hq   = r & 1;
        const int wave = tid >> 6;
        const int lane = tid & 63;
        const int h    = hq * 4 + wave;            // head 0..7

        const int s_begin = sl * SLICE_LEN;
        const int s_end   = min(s_begin + SLICE_LEN, SPOS);

        const float4* lch = (const float4*)ws + (size_t)(h * 4) * SSTRIDE;

        // A row for this head -> 8 SGPRs (readfirstlane)
        float aA[8];
        #pragma unroll
        for (int i = 0; i < 8; ++i)
            aA[i] = __int_as_float(__builtin_amdgcn_readfirstlane(
                        __float_as_int(ws[WS_A_OFF + h * 8 + i])));

        v2f P0[16], P1[16];   // [nb][t2]
        #pragma unroll
        for (int i = 0; i < 16; ++i) { P0[i] = (v2f)(0.f); P1[i] = (v2f)(0.f); }

        const float* simb = sim + (size_t)(bg * 4) * SPOS;

        #pragma unroll 1
        for (int it = 0; it < 7; ++it) {
            const int s = s_begin + it * 64 + lane;
            if (s < s_end) {
                float4 q[4];
                #pragma unroll
                for (int t2 = 0; t2 < 4; ++t2) q[t2] = lch[t2 * SSTRIDE + s];
                float xb[4];
                #pragma unroll
                for (int nb = 0; nb < 4; ++nb) xb[nb] = simb[nb * SPOS + s];

                #pragma unroll
                for (int nb = 0; nb < 4; ++nb) {
                    const float x = xb[nb];
                    const v2f xx = {x, x};
                    v2f e[4];
                    #pragma unroll
                    for (int t2 = 0; t2 < 4; ++t2) {
                        // Horner ((A*x + L)*x + C); first step scalar: A in SGPR
                        const float u0 = fmaf(x, aA[2*t2],   q[t2].x);
                        const float u1 = fmaf(x, aA[2*t2+1], q[t2].y);
                        const v2f uu = {u0, u1};
                        const v2f cv = {q[t2].z, q[t2].w};
                        e[t2] = FMA2(uu, xx, cv);
                    }
                    const v2f m2 = MAX2(MAX2(e[0], e[1]), MAX2(e[2], e[3]));
                    const float m = fmaxf(m2.x, m2.y);
                    const v2f ms = {m, m};
                    v2f den2 = (v2f)(0.f);
                    #pragma unroll
                    for (int t2 = 0; t2 < 4; ++t2) {
                        v2f ee = e[t2] - ms;
                        ee.x = exp2f(ee.x); ee.y = exp2f(ee.y);
                        e[t2] = ee; den2 += ee;
                    }
                    const float inv  = __builtin_amdgcn_rcpf(den2.x + den2.y);
                    const float xinv = x * inv;
                    const v2f vi = {inv, inv}, vx = {xinv, xinv};
                    #pragma unroll
                    for (int t2 = 0; t2 < 4; ++t2) {
                        P0[nb*4+t2] = FMA2(vi, e[t2], P0[nb*4+t2]);
                        P1[nb*4+t2] = FMA2(vx, e[t2], P1[nb*4+t2]);
                    }
                }
            }
        }

        // Flatten: av[nb*16 + t] = P0[nb][t], av[nb*16 + 8 + t] = P1[nb][t]
        float av[64];
        #pragma unroll
        for (int nb = 0; nb < 4; ++nb)
            #pragma unroll
            for (int t = 0; t < 8; ++t) {
                av[nb*16 + t]     = (t & 1) ? P0[nb*4 + (t>>1)].y : P0[nb*4 + (t>>1)].x;
                av[nb*16 + 8 + t] = (t & 1) ? P1[nb*4 + (t>>1)].y : P1[nb*4 + (t>>1)].x;
            }

        // Halving-butterfly across 64 lanes; lane ends with index bitrev6(lane).
        float r32[32];
        #pragma unroll
        for (int i = 0; i < 32; ++i) {
            const bool up = (lane & 1) != 0;
            const float keep = up ? av[i+32] : av[i];
            const float send = up ? av[i]    : av[i+32];
            r32[i] = keep + __shfl_xor(send, 1, 64);
        }
        float r16[16];
        #pragma unroll
        for (int i = 0; i < 16; ++i) {
            const bool up = (lane & 2) != 0;
            const float keep = up ? r32[i+16] : r32[i];
            const float send = up ? r32[i]    : r32[i+16];
            r16[i] = keep + __shfl_xor(send, 2, 64);
        }
        float r8[8];
        #pragma unroll
        for (int i = 0; i < 8; ++i) {
            const bool up = (lane & 4) != 0;
            const float keep = up ? r16[i+8] : r16[i];
            const float send = up ? r16[i]   : r16[i+8];
            r8[i] = keep + __shfl_xor(send, 4, 64);
        }
        float r4[4];
        #pragma unroll
        for (int i = 0; i < 4; ++i) {
            const bool up = (lane & 8) != 0;
            const float keep = up ? r8[i+4] : r8[i];
            const float send = up ? r8[i]   : r8[i+4];
            r4[i] = keep + __shfl_xor(send, 8, 64);
        }
        float r2[2];
        #pragma unroll
        for (int i = 0; i < 2; ++i) {
            const bool up = (lane & 16) != 0;
            const float keep = up ? r4[i+2] : r4[i];
            const float send = up ? r4[i]   : r4[i+2];
            r2[i] = keep + __shfl_xor(send, 16, 64);
        }
        float r1;
        {
            const bool up = (lane & 32) != 0;
            const float keep = up ? r2[1] : r2[0];
            const float send = up ? r2[0] : r2[1];
            r1 = keep + __shfl_xor(send, 32, 64);
        }

        const int f = ((lane & 1) << 5) | ((lane & 2) << 3) | ((lane & 4) << 1)
                    | ((lane & 8) >> 1) | ((lane & 16) >> 3) | ((lane & 32) >> 5);
        const int nb = f >> 4, rem = f & 15;
        ws[WS_PART_OFF +
           ((((size_t)(bg*4 + nb) * 8 + h) * NSLICE + sl) * 16 + rem)] = r1;
    }

    // ---- Last-block-per-bg does phase 2 (no second grid barrier) ----
    __shared__ int s_last;
    __syncthreads();                 // all waves' partial stores before fence
    if (tid == 0) {
        __threadfence();             // publish this block's partials
        const int t = __hip_atomic_fetch_add(&g_cnt[bg], 1, __ATOMIC_ACQ_REL,
                                             __HIP_MEMORY_SCOPE_AGENT);
        s_last = ((t % 12) == 11);   // 12 contributing blocks per bg
    }
    __syncthreads();

    if (s_last) {
        __threadfence();             // acquire: see all 12 blocks' partials
        const float* part = ws + WS_PART_OFF;
        const float* WoT  = ws + WS_WOT_OFF;
        const int wave = tid >> 6;
        const int lane = tid & 63;
        const int b = bg * 4 + wave;           // one batch per wave
        const int l = lane;                    // (h,t) for partials, (h,d) later
        const int h = l >> 3, t = l & 7, d = t;

        float p0 = 0.f, p1 = 0.f;              // P0[h][t], P1[h][t]
        #pragma unroll
        for (int sl = 0; sl < NSLICE; ++sl) {
            const size_t base = (((size_t)b * 8 + h) * NSLICE + sl) * 16;
            p0 += part[base + t];
            p1 += part[base + 8 + t];
        }

        // pooled[h,d] = (sum_t P1[h][t]*wv[t,d] + P0[h][t]*bv[t,d]) / S
        float pool = 0.f;
        #pragma unroll
        for (int tt = 0; tt < 8; ++tt) {
            const float P1v = __shfl(p1, h*8 + tt, 64);
            const float P0v = __shfl(p0, h*8 + tt, 64);
            pool = fmaf(P1v, wv[tt*8 + d], pool);
            pool = fmaf(P0v, bv[tt*8 + d], pool);
        }
        pool *= (1.0f / 2500.0f);

        float y = bo[l];
        #pragma unroll
        for (int j = 0; j < 64; ++j) {
            const float pj = __shfl(pool, j, 64);
            y = fmaf(pj, WoT[j * 64 + l], y);     // coalesced across lanes
        }

        float s1 = y;
        #pragma unroll
        for (int off = 32; off > 0; off >>= 1) s1 += __shfl_xor(s1, off, 64);
        const float mu = s1 * (1.0f / 64.0f);
        const float dlt = y - mu;
        float s2 = dlt * dlt;
        #pragma unroll
        for (int off = 32; off > 0; off >>= 1) s2 += __shfl_xor(s2, off, 64);
        const float var = s2 * (1.0f / 64.0f);

        out[(size_t)b * 64 + l] = dlt * rsqrtf(var + 1e-5f) * gamma[l] + beta[l];
    }
}

extern "C" void kernel_launch(void* const* d_in, const int* in_sizes, int n_in,
                              void* d_out, int out_size, void* d_ws, size_t ws_size,
                              hipStream_t stream) {
    const float* sim   = (const float*)d_in[0];
    const float* wq    = (const float*)d_in[1];
    const float* bq    = (const float*)d_in[2];
    const float* wk    = (const float*)d_in[3];
    const float* bk    = (const float*)d_in[4];
    const float* wv    = (const float*)d_in[5];
    const float* bv    = (const float*)d_in[6];
    const float* pe    = (const float*)d_in[7];
    const float* Wo    = (const float*)d_in[8];
    const float* bo    = (const float*)d_in[9];
    const float* gamma = (const float*)d_in[10];
    const float* beta  = (const float*)d_in[11];
    float* ws  = (float*)d_ws;                 // ~2.1 MB used
    float* out = (float*)d_out;

    attn_pool_fused<<<dim3(NBLOCKS), dim3(256), 0, stream>>>(
        sim, wq, bq, wk, bk, wv, bv, pe, Wo, bo, gamma, beta, ws, out);
}

// Round 9
// 91.296 us; speedup vs baseline: 2.5705x; 1.6746x over previous
//
#include <hip/hip_runtime.h>

typedef float v2f __attribute__((ext_vector_type(2)));
#define FMA2(a,b,c) __builtin_elementwise_fma((a),(b),(c))
#define MAX2(a,b)   __builtin_elementwise_max((a),(b))

#define SPOS 2500
#define SSTRIDE 2560                 // padded column count for LC rows
#define NSLICE 8
// ws layout (floats): LC float4[32][SSTRIDE] | A[64] | WoT[4096] | part[256*8*8*16]
#define WS_A_OFF    (32 * SSTRIDE * 4)
#define WS_WOT_OFF  (WS_A_OFF + 64)
#define WS_PART_OFF (WS_WOT_OFF + 4096)
#define SCL (0.35355339059327373f * 1.4426950408889634f)   // 1/sqrt(8) * log2(e)

// Monotonic per-bg completion counters (never reset; zero at module load).
// Each launch adds exactly 16 arrivals per bg; launches serialize on the
// stream, so (ticket & 15) == 15 identifies the last arrival of THIS launch.
__device__ int g_cnt[64];

// Kernel A: scores are quadratic in x: sc[h][t] = A*x^2 + L*x + C (exp2 dom).
// L,C depend only on pe -> shared by all 256 batches. Row j2 = h*4+t2,
// column s, float4 = (L[2t2], L[2t2+1], C[2t2], C[2t2+1]). Also A[64], WoT.
__global__ __launch_bounds__(256) void attn_pool_pre(
    const float* __restrict__ wq, const float* __restrict__ bq,
    const float* __restrict__ wk, const float* __restrict__ bk,
    const float* __restrict__ pe, const float* __restrict__ Wo,
    float* __restrict__ ws)
{
    const int idx = blockIdx.x * 256 + threadIdx.x;   // 0..24575

    if (idx < SPOS * 8) {
        const int s = idx >> 3, h = idx & 7;

        float per[64];
        const float4* p4 = (const float4*)(pe + (size_t)s * 64);
        #pragma unroll
        for (int j = 0; j < 16; ++j) {
            const float4 t = p4[j];
            per[4*j] = t.x; per[4*j+1] = t.y; per[4*j+2] = t.z; per[4*j+3] = t.w;
        }

        float eq[8];
        #pragma unroll
        for (int d = 0; d < 8; ++d) eq[d] = bq[h*8+d] + per[h*8+d];

        float Lr[8], Cr[8];
        #pragma unroll
        for (int t = 0; t < 8; ++t) {
            float l = 0.f, cc = 0.f;
            #pragma unroll
            for (int d = 0; d < 8; ++d) {
                const float ek = bk[t*8+d] + per[t*8+d];
                l  = fmaf(wq[h*8+d], ek,    l);
                l  = fmaf(wk[t*8+d], eq[d], l);
                cc = fmaf(eq[d], ek, cc);
            }
            Lr[t] = l * SCL; Cr[t] = cc * SCL;
        }

        float4* lc4 = (float4*)ws;
        #pragma unroll
        for (int t2 = 0; t2 < 4; ++t2)
            lc4[(size_t)(h*4+t2) * SSTRIDE + s] =
                make_float4(Lr[2*t2], Lr[2*t2+1], Cr[2*t2], Cr[2*t2+1]);

        if (idx < 64) {
            const int hh = idx >> 3, tt = idx & 7;
            float a = 0.f;
            #pragma unroll
            for (int d = 0; d < 8; ++d) a = fmaf(wq[hh*8+d], wk[tt*8+d], a);
            ws[WS_A_OFF + idx] = a * SCL;
        }
    } else if (idx >= 20480 && idx < 20480 + 4096) {
        const int i = idx - 20480;          // i = j*64 + f
        const int j = i >> 6, f = i & 63;
        ws[WS_WOT_OFF + i] = Wo[(size_t)f * 64 + j];   // WoT[j][f]
    }
}

// Kernel B: phase 1 (exact R5 structure: wave = (head, 4-batch group), lane =
// position, P0/P1 only) + last-arriving-block-per-bg runs the finish (phase 2)
// for its 4 batches. No grid barrier, no spinning.
__global__ __launch_bounds__(256) void attn_pool_main(
    const float* __restrict__ sim,
    const float* __restrict__ wv, const float* __restrict__ bv,
    const float* __restrict__ bo,
    const float* __restrict__ gamma, const float* __restrict__ beta,
    float* __restrict__ ws, float* __restrict__ out)
{
    const int tid  = threadIdx.x;
    const int bg   = blockIdx.x >> 4;          // 0..63: batches bg*4..bg*4+3
    const int sl   = (blockIdx.x >> 1) & 7;    // slice 0..7
    const int hq   = blockIdx.x & 1;
    const int wave = tid >> 6;
    const int lane = tid & 63;
    const int h    = hq * 4 + wave;            // head 0..7

    const int s_begin = (sl * SPOS) >> 3;
    const int s_end   = ((sl + 1) * SPOS) >> 3;   // slices of 312/313

    const float4* lch = (const float4*)ws + (size_t)(h * 4) * SSTRIDE;

    // A row for this head -> 8 SGPRs (readfirstlane)
    float aA[8];
    #pragma unroll
    for (int i = 0; i < 8; ++i)
        aA[i] = __int_as_float(__builtin_amdgcn_readfirstlane(
                    __float_as_int(ws[WS_A_OFF + h * 8 + i])));

    v2f P0[16], P1[16];   // [nb][t2]
    #pragma unroll
    for (int i = 0; i < 16; ++i) { P0[i] = (v2f)(0.f); P1[i] = (v2f)(0.f); }

    const float* simb = sim + (size_t)(bg * 4) * SPOS;

    #pragma unroll 1
    for (int it = 0; it < 5; ++it) {
        const int s = s_begin + it * 64 + lane;
        if (s < s_end) {
            float4 q[4];
            #pragma unroll
            for (int t2 = 0; t2 < 4; ++t2) q[t2] = lch[t2 * SSTRIDE + s];
            float xb[4];
            #pragma unroll
            for (int nb = 0; nb < 4; ++nb) xb[nb] = simb[nb * SPOS + s];

            #pragma unroll
            for (int nb = 0; nb < 4; ++nb) {
                const float x = xb[nb];
                const v2f xx = {x, x};
                v2f e[4];
                #pragma unroll
                for (int t2 = 0; t2 < 4; ++t2) {
                    // Horner ((A*x + L)*x + C); first step scalar: A in SGPR
                    const float u0 = fmaf(x, aA[2*t2],   q[t2].x);
                    const float u1 = fmaf(x, aA[2*t2+1], q[t2].y);
                    const v2f uu = {u0, u1};
                    const v2f cv = {q[t2].z, q[t2].w};
                    e[t2] = FMA2(uu, xx, cv);
                }
                const v2f m2 = MAX2(MAX2(e[0], e[1]), MAX2(e[2], e[3]));
                const float m = fmaxf(m2.x, m2.y);
                const v2f ms = {m, m};
                v2f den2 = (v2f)(0.f);
                #pragma unroll
                for (int t2 = 0; t2 < 4; ++t2) {
                    v2f ee = e[t2] - ms;
                    ee.x = exp2f(ee.x); ee.y = exp2f(ee.y);
                    e[t2] = ee; den2 += ee;
                }
                const float inv  = __builtin_amdgcn_rcpf(den2.x + den2.y);
                const float xinv = x * inv;
                const v2f vi = {inv, inv}, vx = {xinv, xinv};
                #pragma unroll
                for (int t2 = 0; t2 < 4; ++t2) {
                    P0[nb*4+t2] = FMA2(vi, e[t2], P0[nb*4+t2]);
                    P1[nb*4+t2] = FMA2(vx, e[t2], P1[nb*4+t2]);
                }
            }
        }
    }

    // Flatten: av[nb*16 + t] = P0[nb][t], av[nb*16 + 8 + t] = P1[nb][t]
    float av[64];
    #pragma unroll
    for (int nb = 0; nb < 4; ++nb)
        #pragma unroll
        for (int t = 0; t < 8; ++t) {
            av[nb*16 + t]     = (t & 1) ? P0[nb*4 + (t>>1)].y : P0[nb*4 + (t>>1)].x;
            av[nb*16 + 8 + t] = (t & 1) ? P1[nb*4 + (t>>1)].y : P1[nb*4 + (t>>1)].x;
        }

    // Halving-butterfly across 64 lanes; lane ends with index bitrev6(lane).
    float r32[32];
    #pragma unroll
    for (int i = 0; i < 32; ++i) {
        const bool up = (lane & 1) != 0;
        const float keep = up ? av[i+32] : av[i];
        const float send = up ? av[i]    : av[i+32];
        r32[i] = keep + __shfl_xor(send, 1, 64);
    }
    float r16[16];
    #pragma unroll
    for (int i = 0; i < 16; ++i) {
        const bool up = (lane & 2) != 0;
        const float keep = up ? r32[i+16] : r32[i];
        const float send = up ? r32[i]    : r32[i+16];
        r16[i] = keep + __shfl_xor(send, 2, 64);
    }
    float r8[8];
    #pragma unroll
    for (int i = 0; i < 8; ++i) {
        const bool up = (lane & 4) != 0;
        const float keep = up ? r16[i+8] : r16[i];
        const float send = up ? r16[i]   : r16[i+8];
        r8[i] = keep + __shfl_xor(send, 4, 64);
    }
    float r4[4];
    #pragma unroll
    for (int i = 0; i < 4; ++i) {
        const bool up = (lane & 8) != 0;
        const float keep = up ? r8[i+4] : r8[i];
        const float send = up ? r8[i]   : r8[i+4];
        r4[i] = keep + __shfl_xor(send, 8, 64);
    }
    float r2[2];
    #pragma unroll
    for (int i = 0; i < 2; ++i) {
        const bool up = (lane & 16) != 0;
        const float keep = up ? r4[i+2] : r4[i];
        const float send = up ? r4[i]   : r4[i+2];
        r2[i] = keep + __shfl_xor(send, 16, 64);
    }
    float r1;
    {
        const bool up = (lane & 32) != 0;
        const float keep = up ? r2[1] : r2[0];
        const float send = up ? r2[0] : r2[1];
        r1 = keep + __shfl_xor(send, 32, 64);
    }

    const int f = ((lane & 1) << 5) | ((lane & 2) << 3) | ((lane & 4) << 1)
                | ((lane & 8) >> 1) | ((lane & 16) >> 3) | ((lane & 32) >> 5);
    const int nb = f >> 4, rem = f & 15;
    ws[WS_PART_OFF +
       ((((size_t)(bg*4 + nb) * 8 + h) * NSLICE + sl) * 16 + rem)] = r1;

    // ---- Last-arriving block of this bg runs phase 2 (no grid barrier) ----
    __shared__ int s_last;
    __syncthreads();                 // all waves' partial stores issued
    if (tid == 0) {
        __threadfence();             // release: publish this block's partials
        const int t = __hip_atomic_fetch_add(&g_cnt[bg], 1, __ATOMIC_ACQ_REL,
                                             __HIP_MEMORY_SCOPE_AGENT);
        s_last = ((t & 15) == 15);   // 16 contributing blocks per bg per launch
    }
    __syncthreads();

    if (s_last) {
        __threadfence();             // acquire: see all 16 blocks' partials
        const float* part = ws + WS_PART_OFF;
        const float* WoT  = ws + WS_WOT_OFF;
        const int b = bg * 4 + wave;           // one batch per wave
        const int l = lane;                    // (h,t) for partials, (h,d) later
        const int hh = l >> 3, t = l & 7, d = t;

        float p0 = 0.f, p1 = 0.f;              // P0[hh][t], P1[hh][t]
        #pragma unroll
        for (int sl2 = 0; sl2 < NSLICE; ++sl2) {
            const size_t base = (((size_t)b * 8 + hh) * NSLICE + sl2) * 16;
            p0 += part[base + t];
            p1 += part[base + 8 + t];
        }

        // pooled[hh,d] = (sum_t P1[hh][t]*wv[t,d] + P0[hh][t]*bv[t,d]) / S
        float pool = 0.f;
        #pragma unroll
        for (int tt = 0; tt < 8; ++tt) {
            const float P1v = __shfl(p1, hh*8 + tt, 64);
            const float P0v = __shfl(p0, hh*8 + tt, 64);
            pool = fmaf(P1v, wv[tt*8 + d], pool);
            pool = fmaf(P0v, bv[tt*8 + d], pool);
        }
        pool *= (1.0f / 2500.0f);

        float y = bo[l];
        #pragma unroll
        for (int j = 0; j < 64; ++j) {
            const float pj = __shfl(pool, j, 64);
            y = fmaf(pj, WoT[j * 64 + l], y);     // coalesced across lanes
        }

        float s1 = y;
        #pragma unroll
        for (int off = 32; off > 0; off >>= 1) s1 += __shfl_xor(s1, off, 64);
        const float mu = s1 * (1.0f / 64.0f);
        const float dlt = y - mu;
        float s2 = dlt * dlt;
        #pragma unroll
        for (int off = 32; off > 0; off >>= 1) s2 += __shfl_xor(s2, off, 64);
        const float var = s2 * (1.0f / 64.0f);

        out[(size_t)b * 64 + l] = dlt * rsqrtf(var + 1e-5f) * gamma[l] + beta[l];
    }
}

extern "C" void kernel_launch(void* const* d_in, const int* in_sizes, int n_in,
                              void* d_out, int out_size, void* d_ws, size_t ws_size,
                              hipStream_t stream) {
    const float* sim   = (const float*)d_in[0];
    const float* wq    = (const float*)d_in[1];
    const float* bq    = (const float*)d_in[2];
    const float* wk    = (const float*)d_in[3];
    const float* bk    = (const float*)d_in[4];
    const float* wv    = (const float*)d_in[5];
    const float* bv    = (const float*)d_in[6];
    const float* pe    = (const float*)d_in[7];
    const float* Wo    = (const float*)d_in[8];
    const float* bo    = (const float*)d_in[9];
    const float* gamma = (const float*)d_in[10];
    const float* beta  = (const float*)d_in[11];
    float* ws  = (float*)d_ws;                 // ~2.4 MB used
    float* out = (float*)d_out;

    attn_pool_pre <<<dim3(96),   dim3(256), 0, stream>>>(wq, bq, wk, bk, pe, Wo, ws);
    attn_pool_main<<<dim3(1024), dim3(256), 0, stream>>>(sim, wv, bv, bo, gamma, beta, ws, out);
}

// Round 10
// 36.055 us; speedup vs baseline: 6.5089x; 2.5321x over previous
//
#include <hip/hip_runtime.h>

typedef float v2f __attribute__((ext_vector_type(2)));
#define FMA2(a,b,c) __builtin_elementwise_fma((a),(b),(c))
#define MAX2(a,b)   __builtin_elementwise_max((a),(b))

#define SPOS 2500
#define SSTRIDE 2560                 // padded column count for LC rows
#define NSLICE 2
#define SLICE_LEN 1250
// ws layout (floats): LC float4[32][SSTRIDE] | A[64] | WoT[4096] | part[256*8*2*16]
#define WS_A_OFF    (32 * SSTRIDE * 4)
#define WS_WOT_OFF  (WS_A_OFF + 64)
#define WS_PART_OFF (WS_WOT_OFF + 4096)
#define SCL (0.35355339059327373f * 1.4426950408889634f)   // 1/sqrt(8) * log2(e)

// Kernel A: scores are quadratic in x: sc[h][t] = A*x^2 + L*x + C (exp2 dom).
// L,C depend only on pe -> shared by all 256 batches. Row j2 = h*4+t2,
// column s, float4 = (L[2t2], L[2t2+1], C[2t2], C[2t2+1]). Also A[64], WoT.
__global__ __launch_bounds__(256) void attn_pool_pre(
    const float* __restrict__ wq, const float* __restrict__ bq,
    const float* __restrict__ wk, const float* __restrict__ bk,
    const float* __restrict__ pe, const float* __restrict__ Wo,
    float* __restrict__ ws)
{
    const int idx = blockIdx.x * 256 + threadIdx.x;   // 0..24575

    if (idx < SPOS * 8) {
        const int s = idx >> 3, h = idx & 7;

        float per[64];
        const float4* p4 = (const float4*)(pe + (size_t)s * 64);
        #pragma unroll
        for (int j = 0; j < 16; ++j) {
            const float4 t = p4[j];
            per[4*j] = t.x; per[4*j+1] = t.y; per[4*j+2] = t.z; per[4*j+3] = t.w;
        }

        float eq[8];
        #pragma unroll
        for (int d = 0; d < 8; ++d) eq[d] = bq[h*8+d] + per[h*8+d];

        float Lr[8], Cr[8];
        #pragma unroll
        for (int t = 0; t < 8; ++t) {
            float l = 0.f, cc = 0.f;
            #pragma unroll
            for (int d = 0; d < 8; ++d) {
                const float ek = bk[t*8+d] + per[t*8+d];
                l  = fmaf(wq[h*8+d], ek,    l);
                l  = fmaf(wk[t*8+d], eq[d], l);
                cc = fmaf(eq[d], ek, cc);
            }
            Lr[t] = l * SCL; Cr[t] = cc * SCL;
        }

        float4* lc4 = (float4*)ws;
        #pragma unroll
        for (int t2 = 0; t2 < 4; ++t2)
            lc4[(size_t)(h*4+t2) * SSTRIDE + s] =
                make_float4(Lr[2*t2], Lr[2*t2+1], Cr[2*t2], Cr[2*t2+1]);

        if (idx < 64) {
            const int hh = idx >> 3, tt = idx & 7;
            float a = 0.f;
            #pragma unroll
            for (int d = 0; d < 8; ++d) a = fmaf(wq[hh*8+d], wk[tt*8+d], a);
            ws[WS_A_OFF + idx] = a * SCL;
        }
    } else if (idx >= 20480 && idx < 20480 + 4096) {
        const int i = idx - 20480;          // i = j*64 + f
        const int j = i >> 6, f = i & 63;
        ws[WS_WOT_OFF + i] = Wo[(size_t)f * 64 + j];   // WoT[j][f]
    }
}

// Kernel B: wave = (one batch, one head, one half of S); lane = position.
// Minimal per-wave state (P0/P1 = 16 VGPR) so the hot loop fits any VGPR
// budget the allocator picks (incl. 64 regs / 8 waves per SIMD) - no spills.
// LC chunk per (sl,hq) is 40 KB, shared by all 256 batches -> L2-resident.
__global__ __launch_bounds__(256) void attn_pool_k1(
    const float* __restrict__ sim,
    const float* __restrict__ ws, float* __restrict__ part)
{
    const int blk  = blockIdx.x;           // 0..1023
    const int b    = blk >> 2;             // batch 0..255
    const int sl   = (blk >> 1) & 1;       // slice 0..1
    const int hq   = blk & 1;              // head half
    const int wave = threadIdx.x >> 6;
    const int lane = threadIdx.x & 63;
    const int h    = hq * 4 + wave;        // head 0..7

    const int s_begin = sl * SLICE_LEN;
    const int s_end   = s_begin + SLICE_LEN;

    const float4* lch = (const float4*)ws + (size_t)(h * 4) * SSTRIDE;

    // A row for this head -> 8 SGPRs (readfirstlane)
    float aA[8];
    #pragma unroll
    for (int i = 0; i < 8; ++i)
        aA[i] = __int_as_float(__builtin_amdgcn_readfirstlane(
                    __float_as_int(ws[WS_A_OFF + h * 8 + i])));

    v2f P0[4], P1[4];   // [t2] - 16 VGPR total
    #pragma unroll
    for (int i = 0; i < 4; ++i) { P0[i] = (v2f)(0.f); P1[i] = (v2f)(0.f); }

    const float* simb = sim + (size_t)b * SPOS;

    #pragma unroll 1
    for (int it = 0; it < 20; ++it) {
        const int s = s_begin + it * 64 + lane;
        if (s < s_end) {
            float4 q[4];
            #pragma unroll
            for (int t2 = 0; t2 < 4; ++t2) q[t2] = lch[t2 * SSTRIDE + s];
            const float x = simb[s];
            const v2f xx = {x, x};

            v2f e[4];
            #pragma unroll
            for (int t2 = 0; t2 < 4; ++t2) {
                // Horner ((A*x + L)*x + C); first step scalar: A in SGPR
                const float u0 = fmaf(x, aA[2*t2],   q[t2].x);
                const float u1 = fmaf(x, aA[2*t2+1], q[t2].y);
                const v2f uu = {u0, u1};
                const v2f cv = {q[t2].z, q[t2].w};
                e[t2] = FMA2(uu, xx, cv);
            }
            const v2f m2 = MAX2(MAX2(e[0], e[1]), MAX2(e[2], e[3]));
            const float m = fmaxf(m2.x, m2.y);
            const v2f ms = {m, m};
            v2f den2 = (v2f)(0.f);
            #pragma unroll
            for (int t2 = 0; t2 < 4; ++t2) {
                v2f ee = e[t2] - ms;
                ee.x = exp2f(ee.x); ee.y = exp2f(ee.y);
                e[t2] = ee; den2 += ee;
            }
            const float inv  = __builtin_amdgcn_rcpf(den2.x + den2.y);
            const float xinv = x * inv;
            const v2f vi = {inv, inv}, vx = {xinv, xinv};
            #pragma unroll
            for (int t2 = 0; t2 < 4; ++t2) {
                P0[t2] = FMA2(vi, e[t2], P0[t2]);
                P1[t2] = FMA2(vx, e[t2], P1[t2]);
            }
        }
    }

    // Flatten: av[t] = P0[t], av[8+t] = P1[t]  (16 values)
    float av[16];
    #pragma unroll
    for (int t = 0; t < 8; ++t) {
        av[t]     = (t & 1) ? P0[t >> 1].y : P0[t >> 1].x;
        av[8 + t] = (t & 1) ? P1[t >> 1].y : P1[t >> 1].x;
    }

    // Halving-butterfly: 4 halving stages (16->1 regs) + 2 plain stages.
    float r8[8];
    #pragma unroll
    for (int i = 0; i < 8; ++i) {
        const bool up = (lane & 1) != 0;
        const float keep = up ? av[i+8] : av[i];
        const float send = up ? av[i]   : av[i+8];
        r8[i] = keep + __shfl_xor(send, 1, 64);
    }
    float r4[4];
    #pragma unroll
    for (int i = 0; i < 4; ++i) {
        const bool up = (lane & 2) != 0;
        const float keep = up ? r8[i+4] : r8[i];
        const float send = up ? r8[i]   : r8[i+4];
        r4[i] = keep + __shfl_xor(send, 2, 64);
    }
    float r2[2];
    #pragma unroll
    for (int i = 0; i < 2; ++i) {
        const bool up = (lane & 4) != 0;
        const float keep = up ? r2[0] * 0.f + (up ? r4[i+2] : r4[i]) : r4[i]; // placeholder avoided below
        (void)keep;
        const float k2v  = up ? r4[i+2] : r4[i];
        const float send = up ? r4[i]   : r4[i+2];
        r2[i] = k2v + __shfl_xor(send, 4, 64);
    }
    float r1;
    {
        const bool up = (lane & 8) != 0;
        const float keep = up ? r2[1] : r2[0];
        const float send = up ? r2[0] : r2[1];
        r1 = keep + __shfl_xor(send, 8, 64);
    }
    r1 += __shfl_xor(r1, 16, 64);
    r1 += __shfl_xor(r1, 32, 64);

    // lane l (l<16) holds index bitrev4(l): bit0->8, bit1->4, bit2->2, bit3->1
    if (lane < 16) {
        const int idx = ((lane & 1) << 3) | ((lane & 2) << 1)
                      | ((lane & 4) >> 1) | ((lane & 8) >> 3);
        part[(((size_t)b * 8 + h) * NSLICE + sl) * 16 + idx] = r1;
    }
}

// Kernel C: per batch: slice-sum -> wv/bv contraction -> mean -> @WoT + bo -> LN.
__global__ __launch_bounds__(64) void attn_pool_k2(
    const float* __restrict__ ws,
    const float* __restrict__ wv, const float* __restrict__ bv,
    const float* __restrict__ bo,
    const float* __restrict__ gamma, const float* __restrict__ beta,
    float* __restrict__ out)
{
    const float* part = ws + WS_PART_OFF;
    const float* WoT  = ws + WS_WOT_OFF;
    const int b = blockIdx.x;
    const int l = threadIdx.x;           // (h,t) for partials, (h,d) for pooled
    const int h = l >> 3, t = l & 7, d = t;

    float p0 = 0.f, p1 = 0.f;            // P0[h][t], P1[h][t]
    #pragma unroll
    for (int sl = 0; sl < NSLICE; ++sl) {
        const size_t base = (((size_t)b * 8 + h) * NSLICE + sl) * 16;
        p0 += part[base + t];
        p1 += part[base + 8 + t];
    }

    // pooled[h,d] = (sum_t P1[h][t]*wv[t,d] + P0[h][t]*bv[t,d]) / S
    float pool = 0.f;
    #pragma unroll
    for (int tt = 0; tt < 8; ++tt) {
        const float P1v = __shfl(p1, h*8 + tt, 64);
        const float P0v = __shfl(p0, h*8 + tt, 64);
        pool = fmaf(P1v, wv[tt*8 + d], pool);
        pool = fmaf(P0v, bv[tt*8 + d], pool);
    }
    pool *= (1.0f / 2500.0f);

    float y = bo[l];
    #pragma unroll
    for (int j = 0; j < 64; ++j) {
        const float pj = __shfl(pool, j, 64);
        y = fmaf(pj, WoT[j * 64 + l], y);     // coalesced across lanes
    }

    float s1 = y;
    #pragma unroll
    for (int off = 32; off > 0; off >>= 1) s1 += __shfl_xor(s1, off, 64);
    const float mu = s1 * (1.0f / 64.0f);
    const float dlt = y - mu;
    float s2 = dlt * dlt;
    #pragma unroll
    for (int off = 32; off > 0; off >>= 1) s2 += __shfl_xor(s2, off, 64);
    const float var = s2 * (1.0f / 64.0f);

    out[(size_t)b * 64 + l] = dlt * rsqrtf(var + 1e-5f) * gamma[l] + beta[l];
}

extern "C" void kernel_launch(void* const* d_in, const int* in_sizes, int n_in,
                              void* d_out, int out_size, void* d_ws, size_t ws_size,
                              hipStream_t stream) {
    const float* sim   = (const float*)d_in[0];
    const float* wq    = (const float*)d_in[1];
    const float* bq    = (const float*)d_in[2];
    const float* wk    = (const float*)d_in[3];
    const float* bk    = (const float*)d_in[4];
    const float* wv    = (const float*)d_in[5];
    const float* bv    = (const float*)d_in[6];
    const float* pe    = (const float*)d_in[7];
    const float* Wo    = (const float*)d_in[8];
    const float* bo    = (const float*)d_in[9];
    const float* gamma = (const float*)d_in[10];
    const float* beta  = (const float*)d_in[11];
    float* ws   = (float*)d_ws;                 // ~2 MB used
    float* part = ws + WS_PART_OFF;
    float* out  = (float*)d_out;

    attn_pool_pre<<<dim3(96),   dim3(256), 0, stream>>>(wq, bq, wk, bk, pe, Wo, ws);
    attn_pool_k1 <<<dim3(1024), dim3(256), 0, stream>>>(sim, ws, part);
    attn_pool_k2 <<<dim3(256),  dim3(64),  0, stream>>>(ws, wv, bv, bo, gamma, beta, out);
}

// Round 11
// 32.991 us; speedup vs baseline: 7.1133x; 1.0929x over previous
//
#include <hip/hip_runtime.h>

typedef float v2f __attribute__((ext_vector_type(2)));
#define FMA2(a,b,c) __builtin_elementwise_fma((a),(b),(c))
#define MAX2(a,b)   __builtin_elementwise_max((a),(b))

#define SPOS 2500
#define SSTRIDE 2560                 // padded column count for LC rows
#define NSLICE 8
// ws layout (floats): LC float4[32][SSTRIDE] | A[64] | WoT[4096] | part[256*8*8*16]
#define WS_A_OFF    (32 * SSTRIDE * 4)
#define WS_WOT_OFF  (WS_A_OFF + 64)
#define WS_PART_OFF (WS_WOT_OFF + 4096)
#define SCL (0.35355339059327373f * 1.4426950408889634f)   // 1/sqrt(8) * log2(e)

// Kernel A: LC precompute with COALESCED stores (R10's pre had consecutive
// lanes storing 160KB apart). Blocks 0..78: LC for 32 positions each, staged
// through LDS then written as contiguous 512B row-runs. Block 79: A[64].
// Blocks 80..95: WoT.
__global__ __launch_bounds__(256) void attn_pool_pre(
    const float* __restrict__ wq, const float* __restrict__ bq,
    const float* __restrict__ wk, const float* __restrict__ bk,
    const float* __restrict__ pe, const float* __restrict__ Wo,
    float* __restrict__ ws)
{
    const int bx  = blockIdx.x;
    const int tid = threadIdx.x;

    if (bx < 79) {
        __shared__ float4 lds[32][33];       // [j2 row][s_local], +1 pad
        const int s0 = bx * 32;
        const int sl = tid >> 3;             // s_local 0..31
        const int s  = s0 + sl;
        const int h  = tid & 7;

        if (s < SPOS) {
            float per[64];
            const float4* p4 = (const float4*)(pe + (size_t)s * 64);
            #pragma unroll
            for (int j = 0; j < 16; ++j) {
                const float4 t = p4[j];
                per[4*j] = t.x; per[4*j+1] = t.y; per[4*j+2] = t.z; per[4*j+3] = t.w;
            }

            float eq[8];
            #pragma unroll
            for (int d = 0; d < 8; ++d) eq[d] = bq[h*8+d] + per[h*8+d];

            #pragma unroll
            for (int t = 0; t < 8; t += 2) {
                float l0 = 0.f, c0 = 0.f, l1 = 0.f, c1 = 0.f;
                #pragma unroll
                for (int d = 0; d < 8; ++d) {
                    const float ek0 = bk[t*8+d]     + per[t*8+d];
                    const float ek1 = bk[(t+1)*8+d] + per[(t+1)*8+d];
                    l0 = fmaf(wq[h*8+d], ek0,   l0);
                    l0 = fmaf(wk[t*8+d], eq[d], l0);
                    c0 = fmaf(eq[d], ek0, c0);
                    l1 = fmaf(wq[h*8+d], ek1,        l1);
                    l1 = fmaf(wk[(t+1)*8+d], eq[d],  l1);
                    c1 = fmaf(eq[d], ek1, c1);
                }
                lds[h*4 + (t>>1)][sl] =
                    make_float4(l0 * SCL, l1 * SCL, c0 * SCL, c1 * SCL);
            }
        }
        __syncthreads();

        // Store: 32 rows x 32 cols of float4; consecutive tid -> consecutive
        // col -> coalesced 512B runs per half-wave.
        float4* lc4 = (float4*)ws;
        #pragma unroll
        for (int k = 0; k < 4; ++k) {
            const int flat = k * 256 + tid;
            const int row = flat >> 5, col = flat & 31;
            if (s0 + col < SPOS)
                lc4[(size_t)row * SSTRIDE + s0 + col] = lds[row][col];
        }
    } else if (bx == 79) {
        if (tid < 64) {
            const int hh = tid >> 3, tt = tid & 7;
            float a = 0.f;
            #pragma unroll
            for (int d = 0; d < 8; ++d) a = fmaf(wq[hh*8+d], wk[tt*8+d], a);
            ws[WS_A_OFF + tid] = a * SCL;
        }
    } else {
        const int i = (bx - 80) * 256 + tid;   // 0..4095 ; i = j*64 + f
        const int j = i >> 6, f = i & 63;
        ws[WS_WOT_OFF + i] = Wo[(size_t)f * 64 + j];   // WoT[j][f]
    }
}

// Kernel B: wave = (head, 2-batch group, slice); lane = position. LC float4s
// register-shared across 2 batches; next iteration's LC+sim prefetched
// (double-buffered in registers) to hide L2 latency. ~105 VGPR target.
__global__ __launch_bounds__(256) void attn_pool_k1(
    const float* __restrict__ sim,
    const float* __restrict__ ws, float* __restrict__ part)
{
    const int bx   = blockIdx.x;            // 0..2047
    const int bg   = bx >> 4;               // 0..127: batches bg*2, bg*2+1
    const int sl   = (bx >> 1) & 7;         // slice 0..7
    const int hq   = bx & 1;
    const int wave = threadIdx.x >> 6;
    const int lane = threadIdx.x & 63;
    const int h    = hq * 4 + wave;         // head 0..7

    const int s_begin = (sl * SPOS) >> 3;
    const int s_end   = ((sl + 1) * SPOS) >> 3;   // 312/313 positions

    const float4* lch = (const float4*)ws + (size_t)(h * 4) * SSTRIDE;

    // A row for this head -> 8 SGPRs (readfirstlane)
    float aA[8];
    #pragma unroll
    for (int i = 0; i < 8; ++i)
        aA[i] = __int_as_float(__builtin_amdgcn_readfirstlane(
                    __float_as_int(ws[WS_A_OFF + h * 8 + i])));

    v2f P0[8], P1[8];   // [nb][t2] : 32 VGPR
    #pragma unroll
    for (int i = 0; i < 8; ++i) { P0[i] = (v2f)(0.f); P1[i] = (v2f)(0.f); }

    const float* simb = sim + (size_t)(bg * 2) * SPOS;

    // Prefetch iteration 0
    int  s  = s_begin + lane;
    bool v  = s < s_end;
    int  so = v ? s : s_begin;
    float4 q[4];
    #pragma unroll
    for (int t2 = 0; t2 < 4; ++t2) q[t2] = lch[t2 * SSTRIDE + so];
    float xb[2];
    xb[0] = simb[so];
    xb[1] = simb[SPOS + so];

    #pragma unroll 1
    for (int it = 0; it < 5; ++it) {
        // Prefetch next iteration (uniform guard; clamped address)
        float4 qn[4];
        float xn[2];
        if (it < 4) {
            const int sn  = s + 64;
            const int son = (sn < s_end) ? sn : s_begin;
            #pragma unroll
            for (int t2 = 0; t2 < 4; ++t2) qn[t2] = lch[t2 * SSTRIDE + son];
            xn[0] = simb[son];
            xn[1] = simb[SPOS + son];
        }

        if (v) {
            #pragma unroll
            for (int nb = 0; nb < 2; ++nb) {
                const float x = xb[nb];
                const v2f xx = {x, x};
                v2f e[4];
                #pragma unroll
                for (int t2 = 0; t2 < 4; ++t2) {
                    // Horner ((A*x + L)*x + C); first step scalar: A in SGPR
                    const float u0 = fmaf(x, aA[2*t2],   q[t2].x);
                    const float u1 = fmaf(x, aA[2*t2+1], q[t2].y);
                    const v2f uu = {u0, u1};
                    const v2f cv = {q[t2].z, q[t2].w};
                    e[t2] = FMA2(uu, xx, cv);
                }
                const v2f m2 = MAX2(MAX2(e[0], e[1]), MAX2(e[2], e[3]));
                const float m = fmaxf(m2.x, m2.y);
                const v2f ms = {m, m};
                v2f den2 = (v2f)(0.f);
                #pragma unroll
                for (int t2 = 0; t2 < 4; ++t2) {
                    v2f ee = e[t2] - ms;
                    ee.x = exp2f(ee.x); ee.y = exp2f(ee.y);
                    e[t2] = ee; den2 += ee;
                }
                const float inv  = __builtin_amdgcn_rcpf(den2.x + den2.y);
                const float xinv = x * inv;
                const v2f vi = {inv, inv}, vx = {xinv, xinv};
                #pragma unroll
                for (int t2 = 0; t2 < 4; ++t2) {
                    P0[nb*4+t2] = FMA2(vi, e[t2], P0[nb*4+t2]);
                    P1[nb*4+t2] = FMA2(vx, e[t2], P1[nb*4+t2]);
                }
            }
        }

        s += 64;
        v = s < s_end;
        #pragma unroll
        for (int t2 = 0; t2 < 4; ++t2) q[t2] = qn[t2];
        xb[0] = xn[0]; xb[1] = xn[1];
    }

    // Flatten: av[nb*16 + t] = P0[nb][t], av[nb*16 + 8 + t] = P1[nb][t]
    float av[32];
    #pragma unroll
    for (int nb = 0; nb < 2; ++nb)
        #pragma unroll
        for (int t = 0; t < 8; ++t) {
            av[nb*16 + t]     = (t & 1) ? P0[nb*4 + (t>>1)].y : P0[nb*4 + (t>>1)].x;
            av[nb*16 + 8 + t] = (t & 1) ? P1[nb*4 + (t>>1)].y : P1[nb*4 + (t>>1)].x;
        }

    // Halving-butterfly: 5 stages over lane bits 0..4 (32 values -> 1),
    // then a plain xor-32 add for the full 64-lane sum.
    float r16[16];
    #pragma unroll
    for (int i = 0; i < 16; ++i) {
        const bool up = (lane & 1) != 0;
        const float keep = up ? av[i+16] : av[i];
        const float send = up ? av[i]    : av[i+16];
        r16[i] = keep + __shfl_xor(send, 1, 64);
    }
    float r8[8];
    #pragma unroll
    for (int i = 0; i < 8; ++i) {
        const bool up = (lane & 2) != 0;
        const float keep = up ? r16[i+8] : r16[i];
        const float send = up ? r16[i]   : r16[i+8];
        r8[i] = keep + __shfl_xor(send, 2, 64);
    }
    float r4[4];
    #pragma unroll
    for (int i = 0; i < 4; ++i) {
        const bool up = (lane & 4) != 0;
        const float keep = up ? r4[0]*0.f + (up ? r8[i+4] : r8[i]) : r8[i];
        (void)keep;
        const float kv   = up ? r8[i+4] : r8[i];
        const float send = up ? r8[i]   : r8[i+4];
        r4[i] = kv + __shfl_xor(send, 4, 64);
    }
    float r2[2];
    #pragma unroll
    for (int i = 0; i < 2; ++i) {
        const bool up = (lane & 8) != 0;
        const float kv   = up ? r4[i+2] : r4[i];
        const float send = up ? r4[i]   : r4[i+2];
        r2[i] = kv + __shfl_xor(send, 8, 64);
    }
    float r1;
    {
        const bool up = (lane & 16) != 0;
        const float kv   = up ? r2[1] : r2[0];
        const float send = up ? r2[0] : r2[1];
        r1 = kv + __shfl_xor(send, 16, 64);
    }
    r1 += __shfl_xor(r1, 32, 64);

    // lane l<32 holds av-index f = bitrev5(l): bits 0..4 reversed.
    if (lane < 32) {
        const int f = ((lane & 1) << 4) | ((lane & 2) << 2) | (lane & 4)
                    | ((lane & 8) >> 2) | ((lane & 16) >> 4);
        const int nb = f >> 4, rem = f & 15;
        part[(((size_t)(bg*2 + nb) * 8 + h) * NSLICE + sl) * 16 + rem] = r1;
    }
}

// Kernel C: per batch: slice-sum -> wv/bv contraction -> mean -> @WoT + bo -> LN.
// y accumulated in 4 independent chains for load/fma ILP.
__global__ __launch_bounds__(64) void attn_pool_k2(
    const float* __restrict__ ws,
    const float* __restrict__ wv, const float* __restrict__ bv,
    const float* __restrict__ bo,
    const float* __restrict__ gamma, const float* __restrict__ beta,
    float* __restrict__ out)
{
    const float* part = ws + WS_PART_OFF;
    const float* WoT  = ws + WS_WOT_OFF;
    const int b = blockIdx.x;
    const int l = threadIdx.x;           // (h,t) for partials, (h,d) for pooled
    const int h = l >> 3, t = l & 7, d = t;

    float p0 = 0.f, p1 = 0.f;            // P0[h][t], P1[h][t]
    #pragma unroll
    for (int sl = 0; sl < NSLICE; ++sl) {
        const size_t base = (((size_t)b * 8 + h) * NSLICE + sl) * 16;
        p0 += part[base + t];
        p1 += part[base + 8 + t];
    }

    // pooled[h,d] = (sum_t P1[h][t]*wv[t,d] + P0[h][t]*bv[t,d]) / S
    float pool = 0.f;
    #pragma unroll
    for (int tt = 0; tt < 8; ++tt) {
        const float P1v = __shfl(p1, h*8 + tt, 64);
        const float P0v = __shfl(p0, h*8 + tt, 64);
        pool = fmaf(P1v, wv[tt*8 + d], pool);
        pool = fmaf(P0v, bv[tt*8 + d], pool);
    }
    pool *= (1.0f / 2500.0f);

    // y = bo + WoT^T-row dot pooled; 4 independent accumulation chains
    float y0 = 0.f, y1 = 0.f, y2 = 0.f, y3 = 0.f;
    #pragma unroll
    for (int j = 0; j < 64; j += 4) {
        const float pj0 = __shfl(pool, j + 0, 64);
        const float pj1 = __shfl(pool, j + 1, 64);
        const float pj2 = __shfl(pool, j + 2, 64);
        const float pj3 = __shfl(pool, j + 3, 64);
        y0 = fmaf(pj0, WoT[(j + 0) * 64 + l], y0);
        y1 = fmaf(pj1, WoT[(j + 1) * 64 + l], y1);
        y2 = fmaf(pj2, WoT[(j + 2) * 64 + l], y2);
        y3 = fmaf(pj3, WoT[(j + 3) * 64 + l], y3);
    }
    const float y = bo[l] + ((y0 + y1) + (y2 + y3));

    float s1 = y;
    #pragma unroll
    for (int off = 32; off > 0; off >>= 1) s1 += __shfl_xor(s1, off, 64);
    const float mu = s1 * (1.0f / 64.0f);
    const float dlt = y - mu;
    float s2 = dlt * dlt;
    #pragma unroll
    for (int off = 32; off > 0; off >>= 1) s2 += __shfl_xor(s2, off, 64);
    const float var = s2 * (1.0f / 64.0f);

    out[(size_t)b * 64 + l] = dlt * rsqrtf(var + 1e-5f) * gamma[l] + beta[l];
}

extern "C" void kernel_launch(void* const* d_in, const int* in_sizes, int n_in,
                              void* d_out, int out_size, void* d_ws, size_t ws_size,
                              hipStream_t stream) {
    const float* sim   = (const float*)d_in[0];
    const float* wq    = (const float*)d_in[1];
    const float* bq    = (const float*)d_in[2];
    const float* wk    = (const float*)d_in[3];
    const float* bk    = (const float*)d_in[4];
    const float* wv    = (const float*)d_in[5];
    const float* bv    = (const float*)d_in[6];
    const float* pe    = (const float*)d_in[7];
    const float* Wo    = (const float*)d_in[8];
    const float* bo    = (const float*)d_in[9];
    const float* gamma = (const float*)d_in[10];
    const float* beta  = (const float*)d_in[11];
    float* ws   = (float*)d_ws;                 // ~2.4 MB used
    float* part = ws + WS_PART_OFF;
    float* out  = (float*)d_out;

    attn_pool_pre<<<dim3(96),   dim3(256), 0, stream>>>(wq, bq, wk, bk, pe, Wo, ws);
    attn_pool_k1 <<<dim3(2048), dim3(256), 0, stream>>>(sim, ws, part);
    attn_pool_k2 <<<dim3(256),  dim3(64),  0, stream>>>(ws, wv, bv, bo, gamma, beta, out);
}